// Round 6
// baseline (106.914 us; speedup 1.0000x reference)
//
#include <hip/hip_runtime.h>
#include <hip/hip_bf16.h>

#define BATCH 8192
#define DIN   4096
#define H1    128
#define NLAT  512
#define LAT   32
#define BM    16
#define BK    128
#define NSTEP (DIN / BK)   // 32
#define APITCH 136         // ushorts per LDS row (128 + 8 pad -> bank spread)

typedef short bf16x8 __attribute__((ext_vector_type(8)));
typedef short bf16x4 __attribute__((ext_vector_type(4)));
typedef float f32x4  __attribute__((ext_vector_type(4)));

static __device__ __forceinline__ unsigned short f2bf(float f) {
  union { float f; unsigned u; } v; v.f = f;
  return (unsigned short)((v.u + 0x7FFFu + ((v.u >> 16) & 1u)) >> 16);  // RNE
}

static __device__ __forceinline__ void cvtw4(unsigned short* p, f32x4 v) {
  union { bf16x4 v; unsigned short u[4]; } o;
#pragma unroll
  for (int j = 0; j < 4; j++) o.u[j] = f2bf(v[j]);
  *(bf16x4*)p = o.v;
}

// ---- prep_all: three independent repacks, branched on blockIdx.
// b in [0,256):   W1 [4096][128] -> W1B fragment-packed bf16 (1 MB)
// b in [256,288): W2 [128][512]  -> W2B fragment-packed bf16 (128 KB)
// b in [288,416): decoders flat [4096][32] -> decT [32][4096] f32
// Fragment packing: group gi=(k32, cf): lane(g=lane>>4, fr=lane&15), elem j
//   holds W[k32*32 + g*8 + j][cf*16 + fr] -> wave load = contiguous 1KB. ----
__global__ void prep_all(const float* __restrict__ W1, const float* __restrict__ W2,
                         const float* __restrict__ dec,
                         unsigned short* __restrict__ W1B,
                         unsigned short* __restrict__ W2B,
                         float* __restrict__ decT) {
  int b = blockIdx.x;
  int t = threadIdx.x;
  if (b < 256) {
    int gi = (b << 2) + (t >> 6);         // k32*8 + cf, 0..1023
    int lane = t & 63;
    int kb = ((gi >> 3) << 5) + ((lane >> 4) << 3);
    int c = ((gi & 7) << 4) + (lane & 15);
    union { bf16x8 v; unsigned short u[8]; } o;
#pragma unroll
    for (int j = 0; j < 8; j++) o.u[j] = f2bf(W1[(size_t)(kb + j) * H1 + c]);
    *(bf16x8*)(W1B + (((size_t)gi << 6) + lane) * 8) = o.v;
  } else if (b < 288) {
    int gi = ((b - 256) << 2) + (t >> 6); // k32*32 + cf, 0..127
    int lane = t & 63;
    int kb = ((gi >> 5) << 5) + ((lane >> 4) << 3);
    int c = ((gi & 31) << 4) + (lane & 15);
    union { bf16x8 v; unsigned short u[8]; } o;
#pragma unroll
    for (int j = 0; j < 8; j++) o.u[j] = f2bf(W2[(size_t)(kb + j) * NLAT + c]);
    *(bf16x8*)(W2B + (((size_t)gi << 6) + lane) * 8) = o.v;
  } else {
    __shared__ float tbuf[32][33];
    int d0 = (b - 288) * 32;
    int tx = t & 31, ty = t >> 5;
#pragma unroll
    for (int i = 0; i < 32; i += 8)
      tbuf[ty + i][tx] = dec[(size_t)(d0 + ty + i) * LAT + tx];
    __syncthreads();
#pragma unroll
    for (int i = 0; i < 32; i += 8)
      decT[(size_t)(ty + i) * DIN + (d0 + tx)] = tbuf[tx][ty + i];
  }
}

// ---- fused_kernel: per block of 16 rows, full pipeline:
// A: h = relu(x@W1+b1)  (bf16 MFMA; x LDS-staged dbuf, reg-prefetch depth 4)
// B: z = h@W2+b2 -> zout; zsum fold (LDS) -> zs[16][32]
// C: recon = zs @ decT -> rout  (f32 vector, write-bound)
// Grid: 512 blocks (2/CU) x 512 thr (8 waves) -> phases of co-resident
// blocks overlap (A's HBM reads hide C's writes). ----
__global__ __launch_bounds__(512, 2) void fused_kernel(
    const float* __restrict__ x, const unsigned short* __restrict__ W1B,
    const unsigned short* __restrict__ W2B,
    const float* __restrict__ b1, const float* __restrict__ b2,
    const float* __restrict__ decT,
    float* __restrict__ zout, float* __restrict__ rout) {
  __shared__ unsigned short As[2][BM * APITCH];
  __shared__ unsigned short hs[BM * APITCH];
  __shared__ float zsp[8][BM][32];
  __shared__ float zs[BM][32];

  const int t = threadIdx.x;
  const int rbase = blockIdx.x << 4;
  const int w = t >> 6, lane = t & 63;
  const int g = lane >> 4, fr = lane & 15;

  // ---- phase A ----
  // staging: thread -> row t>>5, 4 f32 at k-offset (t&31)*4 (16B coalesced)
  const int srow = t >> 5, skq = (t & 31) << 2;
  const float* xp = x + (size_t)(rbase + srow) * DIN + skq;
  const int wofs = srow * APITCH + skq;

  f32x4 acc = (f32x4){0.f, 0.f, 0.f, 0.f};

  // prologue: stage step 0 directly; prefetch steps 1..4 into named regs
  cvtw4(&As[0][wofs], *(const f32x4*)xp);
  f32x4 pf1 = *(const f32x4*)(xp + 1 * BK);
  f32x4 pf2 = *(const f32x4*)(xp + 2 * BK);
  f32x4 pf3 = *(const f32x4*)(xp + 3 * BK);
  f32x4 pf0 = *(const f32x4*)(xp + 4 * BK);
  __syncthreads();

  // step s: MFMA on buf[s&1]; ds_write step s+1 (loaded 4 steps ago) into
  // buf[(s+1)&1]; issue load for step s+5 into the freed slot; barrier.
#define ASTEP(S, PF) do {                                                    \
    const unsigned short* ab = &As[(S) & 1][0];                              \
    _Pragma("unroll")                                                        \
    for (int k32 = 0; k32 < 4; ++k32) {                                      \
      bf16x8 bv = *(const bf16x8*)(W1B +                                     \
          ((((size_t)(((S) << 2) + k32) << 3) + w) << 9) + (lane << 3));     \
      bf16x8 a0 = *(const bf16x8*)(ab + fr * APITCH + (((k32 << 2) + g) << 3)); \
      acc = __builtin_amdgcn_mfma_f32_16x16x32_bf16(a0, bv, acc, 0, 0, 0);   \
    }                                                                        \
    if ((S) + 1 < NSTEP) {                                                   \
      cvtw4(&As[((S) + 1) & 1][wofs], PF);                                   \
      if ((S) + 5 < NSTEP) PF = *(const f32x4*)(xp + ((S) + 5) * BK);        \
    }                                                                        \
    __syncthreads();                                                         \
  } while (0)

  for (int s = 0; s < NSTEP; s += 4) {
    ASTEP(s, pf1);
    ASTEP(s + 1, pf2);
    ASTEP(s + 2, pf3);
    ASTEP(s + 3, pf0);
  }
#undef ASTEP

  // phase A epilogue: +b1, relu -> hs (bf16). C/D: col=fr, row=g*4+j.
  {
    const int col = (w << 4) + fr;
    const float b1v = b1[col];
#pragma unroll
    for (int j = 0; j < 4; j++) {
      float h = fmaxf(acc[j] + b1v, 0.f);
      hs[((g << 2) + j) * APITCH + col] = f2bf(h);
    }
  }
  __syncthreads();

  // ---- phase B: z = h @ W2 + b2. Wave w: 16 rows x cols w*64..+64. ----
  f32x4 acc2[4];
#pragma unroll
  for (int i = 0; i < 4; i++) acc2[i] = (f32x4){0.f, 0.f, 0.f, 0.f};
#pragma unroll
  for (int k32 = 0; k32 < 4; ++k32) {
    bf16x8 a0 = *(const bf16x8*)(hs + fr * APITCH + (((k32 << 2) + g) << 3));
#pragma unroll
    for (int cfl = 0; cfl < 4; ++cfl) {
      bf16x8 bv = *(const bf16x8*)(W2B +
          (((size_t)((k32 << 5) + (w << 2) + cfl)) << 9) + (lane << 3));
      acc2[cfl] = __builtin_amdgcn_mfma_f32_16x16x32_bf16(a0, bv, acc2[cfl], 0, 0, 0);
    }
  }
  // epilogue: z write + zsum fold. col = w*64+cfl*16+fr;
  // latent = (cfl&1)*16+fr; factor = w*2 + (cfl>>1).
  {
    f32x4 zv[4];
#pragma unroll
    for (int cfl = 0; cfl < 4; ++cfl) {
      const float b2v = b2[(w << 6) + (cfl << 4) + fr];
#pragma unroll
      for (int j = 0; j < 4; j++) zv[cfl][j] = acc2[cfl][j] + b2v;
    }
    const int row0 = g << 2;
#pragma unroll
    for (int j = 0; j < 4; j++) {
#pragma unroll
      for (int cfl = 0; cfl < 4; ++cfl)
        zout[(size_t)(rbase + row0 + j) * NLAT + (w << 6) + (cfl << 4) + fr] = zv[cfl][j];
      zsp[w][row0 + j][fr]      = zv[0][j] + zv[2][j];
      zsp[w][row0 + j][16 + fr] = zv[1][j] + zv[3][j];
    }
  }
  __syncthreads();
  // reduce 8 wave-partials -> zs (512 threads = 16x32 exactly)
  {
    const int r = t >> 5, l = t & 31;
    float s = 0.f;
#pragma unroll
    for (int w8 = 0; w8 < 8; w8++) s += zsp[w8][r][l];
    zs[r][l] = s;
  }
  __syncthreads();

  // ---- phase C: recon. Wave w: all 16 rows, cols [w*512, +512),
  // 2 passes of 256 cols; acc a[16] f32x4 (static-indexed). ----
  const int dbase = (w << 9) + (lane << 2);
#pragma unroll
  for (int pass = 0; pass < 2; ++pass) {
    const int dcol = dbase + (pass << 8);
    f32x4 a[16];
#pragma unroll
    for (int r = 0; r < 16; ++r) a[r] = (f32x4){0.f, 0.f, 0.f, 0.f};
#pragma unroll 4
    for (int l = 0; l < 32; ++l) {
      f32x4 dv = *(const f32x4*)(decT + (size_t)l * DIN + dcol);
#pragma unroll
      for (int r = 0; r < 16; ++r) {
        const float zvv = zs[r][l];
#pragma unroll
        for (int j = 0; j < 4; j++) a[r][j] += zvv * dv[j];
      }
    }
#pragma unroll
    for (int r = 0; r < 16; ++r)
      *(f32x4*)(rout + (size_t)(rbase + r) * DIN + dcol) = a[r];
  }
}

extern "C" void kernel_launch(void* const* d_in, const int* in_sizes, int n_in,
                              void* d_out, int out_size, void* d_ws, size_t ws_size,
                              hipStream_t stream) {
  const float* x   = (const float*)d_in[0];
  const float* W1  = (const float*)d_in[1];
  const float* b1  = (const float*)d_in[2];
  const float* W2  = (const float*)d_in[3];
  const float* b2  = (const float*)d_in[4];
  const float* dec = (const float*)d_in[5];
  float* zout = (float*)d_out;
  float* rout = zout + (size_t)BATCH * NLAT;

  char* ws = (char*)d_ws;
  unsigned short* W1B = (unsigned short*)ws;                 // 1 MB
  unsigned short* W2B = (unsigned short*)(ws + (1u << 20));  // 128 KB
  float* decT = (float*)(ws + (1u << 20) + (1u << 17));      // 512 KB

  prep_all<<<dim3(416), 256, 0, stream>>>(W1, W2, dec, W1B, W2B, decT);
  fused_kernel<<<dim3(BATCH / BM), 512, 0, stream>>>(x, W1B, W2B, b1, b2, decT, zout, rout);
}

// Round 7
// 90.933 us; speedup vs baseline: 1.1758x; 1.1758x over previous
//
#include <hip/hip_runtime.h>
#include <hip/hip_bf16.h>

#define BATCH 8192
#define DIN   4096
#define H1    128
#define NLAT  512
#define LAT   32
#define BM    16
#define BK    128
#define NSTEP (DIN / BK)   // 32
#define APITCH 136         // ushorts per LDS row (128 + 8 pad)

typedef short bf16x8 __attribute__((ext_vector_type(8)));
typedef float f32x4  __attribute__((ext_vector_type(4)));

static __device__ __forceinline__ unsigned short f2bf(float f) {
  union { float f; unsigned u; } v; v.f = f;
  return (unsigned short)((v.u + 0x7FFFu + ((v.u >> 16) & 1u)) >> 16);  // RNE
}

static __device__ __forceinline__ void cvtw8(unsigned short* p, f32x4 a, f32x4 b) {
  union { bf16x8 v; unsigned short u[8]; } o;
#pragma unroll
  for (int j = 0; j < 4; j++) { o.u[j] = f2bf(a[j]); o.u[4 + j] = f2bf(b[j]); }
  *(bf16x8*)p = o.v;
}

// ---- prep_all: W1 -> W1B frag-packed bf16; W2 -> W2B frag-packed bf16;
// decoders -> decT [32][4096] f32. Fragment packing (gi = k32*NCF + cf):
// elem j of lane (g=lane>>4, fr=lane&15) holds W[k32*32+g*8+j][cf*16+fr],
// so a wave's fragment load is one contiguous 1KB dwordx4. ----
__global__ void prep_all(const float* __restrict__ W1, const float* __restrict__ W2,
                         const float* __restrict__ dec,
                         unsigned short* __restrict__ W1B,
                         unsigned short* __restrict__ W2B,
                         float* __restrict__ decT) {
  int b = blockIdx.x;
  int t = threadIdx.x;
  if (b < 256) {
    int gi = (b << 2) + (t >> 6);         // k32*8 + cf, 0..1023
    int lane = t & 63;
    int kb = ((gi >> 3) << 5) + ((lane >> 4) << 3);
    int c = ((gi & 7) << 4) + (lane & 15);
    union { bf16x8 v; unsigned short u[8]; } o;
#pragma unroll
    for (int j = 0; j < 8; j++) o.u[j] = f2bf(W1[(size_t)(kb + j) * H1 + c]);
    *(bf16x8*)(W1B + (((size_t)gi << 6) + (lane & 63)) * 8) = o.v;
  } else if (b < 288) {
    int gi = ((b - 256) << 2) + (t >> 6); // k32*32 + cf, 0..127
    int lane = t & 63;
    int kb = ((gi >> 5) << 5) + ((lane >> 4) << 3);
    int c = ((gi & 31) << 4) + (lane & 15);
    union { bf16x8 v; unsigned short u[8]; } o;
#pragma unroll
    for (int j = 0; j < 8; j++) o.u[j] = f2bf(W2[(size_t)(kb + j) * NLAT + c]);
    *(bf16x8*)(W2B + (((size_t)gi << 6) + lane) * 8) = o.v;
  } else {
    __shared__ float tbuf[32][33];
    int d0 = (b - 288) * 32;
    int tx = t & 31, ty = t >> 5;
#pragma unroll
    for (int i = 0; i < 32; i += 8)
      tbuf[ty + i][tx] = dec[(size_t)(d0 + ty + i) * LAT + tx];
    __syncthreads();
#pragma unroll
    for (int i = 0; i < 32; i += 8)
      decT[(size_t)(ty + i) * DIN + (d0 + tx)] = tbuf[tx][ty + i];
  }
}

// ---- enc_kernel: h = relu(x@W1+b1); z = h@W2+b2 -> zout; zsum -> zsumg.
// 256 thr (4 waves), BM=16 rows, full K. Grid 512 = 2 blocks/CU issued,
// __launch_bounds__(256,4) -> 4 co-resident blocks/CU: different blocks sit
// at different pipeline phases, covering each barrier's vmcnt drain (TLP).
// Phase A: wave w -> cols w*32..+32 (2 col-frags). Phase B: cols w*128..+128
// (8 col-frags). ----
__global__ __launch_bounds__(256, 4) void enc_kernel(
    const float* __restrict__ x, const unsigned short* __restrict__ W1B,
    const unsigned short* __restrict__ W2B,
    const float* __restrict__ b1, const float* __restrict__ b2,
    float* __restrict__ zout, float* __restrict__ zsumg) {
  __shared__ unsigned short As[2][BM * APITCH];  // 2 x 4.25 KB
  __shared__ unsigned short hs[BM * APITCH];
  __shared__ float zsp[4][BM][33];               // padded: write conflict-free

  const int t = threadIdx.x;
  const int rbase = blockIdx.x << 4;
  const int w = t >> 6, lane = t & 63;
  const int g = lane >> 4, fr = lane & 15;

  // staging: thread -> row t>>4 (16/row), 8 f32 at col (t&15)*8 (32B chunks)
  const int srow = t >> 4, skq = (t & 15) << 3;
  const float* xp = x + (size_t)(rbase + srow) * DIN + skq;
  const int wofs = srow * APITCH + skq;

  f32x4 acc[2];
  acc[0] = (f32x4){0.f, 0.f, 0.f, 0.f};
  acc[1] = (f32x4){0.f, 0.f, 0.f, 0.f};

  // prologue: stage step 0
  cvtw8(&As[0][wofs], *(const f32x4*)xp, *(const f32x4*)(xp + 4));
  __syncthreads();

  for (int s = 0; s < NSTEP; ++s) {
    f32x4 ra0, ra1;
    const bool more = (s + 1) < NSTEP;
    if (more) {  // issue next-step loads before compute
      ra0 = *(const f32x4*)(xp + (s + 1) * BK);
      ra1 = *(const f32x4*)(xp + (s + 1) * BK + 4);
    }
    const unsigned short* ab = &As[s & 1][0];
#pragma unroll
    for (int k32 = 0; k32 < 4; ++k32) {
      bf16x8 a0 = *(const bf16x8*)(ab + fr * APITCH + (((k32 << 2) + g) << 3));
#pragma unroll
      for (int cc = 0; cc < 2; ++cc) {
        bf16x8 bv = *(const bf16x8*)(W1B +
            ((((size_t)(((s << 2) + k32) << 3)) + (w << 1) + cc) << 9) + (lane << 3));
        acc[cc] = __builtin_amdgcn_mfma_f32_16x16x32_bf16(a0, bv, acc[cc], 0, 0, 0);
      }
    }
    if (more)
      cvtw8(&As[(s + 1) & 1][wofs], ra0, ra1);
    __syncthreads();
  }

  // phase A epilogue: +b1, relu -> hs bf16. C/D: col=fr (N), row=g*4+j (M).
  {
#pragma unroll
    for (int cc = 0; cc < 2; ++cc) {
      const int col = (w << 5) + (cc << 4) + fr;
      const float b1v = b1[col];
#pragma unroll
      for (int j = 0; j < 4; j++) {
        float h = fmaxf(acc[cc][j] + b1v, 0.f);
        hs[((g << 2) + j) * APITCH + col] = f2bf(h);
      }
    }
  }
  __syncthreads();

  // phase B: z = h @ W2 + b2. Wave w: 16 rows x cols w*128..+128 (cf2=w*8+cc).
  f32x4 acc2[8];
#pragma unroll
  for (int i = 0; i < 8; i++) acc2[i] = (f32x4){0.f, 0.f, 0.f, 0.f};
#pragma unroll
  for (int k32 = 0; k32 < 4; ++k32) {
    bf16x8 a0 = *(const bf16x8*)(hs + fr * APITCH + (((k32 << 2) + g) << 3));
#pragma unroll
    for (int cc = 0; cc < 8; ++cc) {
      bf16x8 bv = *(const bf16x8*)(W2B +
          (((size_t)((k32 << 5) + (w << 3) + cc)) << 9) + (lane << 3));
      acc2[cc] = __builtin_amdgcn_mfma_f32_16x16x32_bf16(a0, bv, acc2[cc], 0, 0, 0);
    }
  }

  // epilogue: z write + zsum fold. col = w*128 + cc*16 + fr;
  // latent l = (cc&1)*16 + fr; factor = w*4 + cc/2.
  {
    f32x4 zv[8];
#pragma unroll
    for (int cc = 0; cc < 8; ++cc) {
      const float b2v = b2[(w << 7) + (cc << 4) + fr];
#pragma unroll
      for (int j = 0; j < 4; j++) zv[cc][j] = acc2[cc][j] + b2v;
    }
    const int row0 = g << 2;
#pragma unroll
    for (int j = 0; j < 4; j++) {
#pragma unroll
      for (int cc = 0; cc < 8; ++cc)
        zout[(size_t)(rbase + row0 + j) * NLAT + (w << 7) + (cc << 4) + fr] = zv[cc][j];
      zsp[w][row0 + j][fr]      = zv[0][j] + zv[2][j] + zv[4][j] + zv[6][j];
      zsp[w][row0 + j][16 + fr] = zv[1][j] + zv[3][j] + zv[5][j] + zv[7][j];
    }
  }
  __syncthreads();
  // reduce 4 wave-partials -> zsumg (256 thr x 2 = 512 entries)
#pragma unroll
  for (int i = 0; i < 2; i++) {
    int idx = t + (i << 8);
    int r = idx >> 5, l = idx & 31;
    float s = zsp[0][r][l] + zsp[1][r][l] + zsp[2][r][l] + zsp[3][r][l];
    zsumg[(size_t)(rbase + r) * LAT + l] = s;
  }
}

// ---- recon_kernel: rout[b][d] = sum_l zsum[b][l] * decT[l][d]. ----
__global__ __launch_bounds__(256) void recon_kernel(
    const float* __restrict__ zsumg, const float* __restrict__ decT,
    float* __restrict__ rout) {
  __shared__ float zs[32][32];
  int t = threadIdx.x;
  int rbase = (blockIdx.x >> 4) << 5;
  int dcol0 = (blockIdx.x & 15) << 8;
  {
    int r = t >> 3, c4 = (t & 7) << 2;
    *(f32x4*)&zs[r][c4] = *(const f32x4*)(zsumg + (size_t)(rbase + r) * LAT + c4);
  }
  __syncthreads();
  int wq = t >> 6, lane = t & 63;
  int r0 = wq << 3;
  int dcol = dcol0 + (lane << 2);
  f32x4 acc[8];
#pragma unroll
  for (int r = 0; r < 8; r++) acc[r] = (f32x4){0.f, 0.f, 0.f, 0.f};
#pragma unroll 4
  for (int l = 0; l < 32; l++) {
    f32x4 dv = *(const f32x4*)(decT + (size_t)l * DIN + dcol);
#pragma unroll
    for (int r = 0; r < 8; r++) {
      float zv = zs[r0 + r][l];
#pragma unroll
      for (int j = 0; j < 4; j++) acc[r][j] += zv * dv[j];
    }
  }
#pragma unroll
  for (int r = 0; r < 8; r++)
    *(f32x4*)(rout + (size_t)(rbase + r0 + r) * DIN + dcol) = acc[r];
}

extern "C" void kernel_launch(void* const* d_in, const int* in_sizes, int n_in,
                              void* d_out, int out_size, void* d_ws, size_t ws_size,
                              hipStream_t stream) {
  const float* x   = (const float*)d_in[0];
  const float* W1  = (const float*)d_in[1];
  const float* b1  = (const float*)d_in[2];
  const float* W2  = (const float*)d_in[3];
  const float* b2  = (const float*)d_in[4];
  const float* dec = (const float*)d_in[5];
  float* zout = (float*)d_out;
  float* rout = zout + (size_t)BATCH * NLAT;

  char* ws = (char*)d_ws;
  unsigned short* W1B = (unsigned short*)ws;                          // 1 MB
  unsigned short* W2B = (unsigned short*)(ws + (1u << 20));           // 128 KB
  float* decT  = (float*)(ws + (1u << 20) + (1u << 17));              // 512 KB
  float* zsumg = (float*)(ws + (1u << 20) + (1u << 17) + (1u << 19)); // 1 MB

  prep_all<<<dim3(416), 256, 0, stream>>>(W1, W2, dec, W1B, W2B, decT);
  enc_kernel<<<dim3(BATCH / BM), 256, 0, stream>>>(x, W1B, W2B, b1, b2, zout, zsumg);
  recon_kernel<<<dim3(4096), 256, 0, stream>>>(zsumg, decT, rout);
}